// Round 16
// baseline (101.014 us; speedup 1.0000x reference)
//
#include <hip/hip_runtime.h>

#define DM 768
#define NHEAD 8
#define HDIM 96
#define NB 8
#define SEQ 8192
#define NA 512
#define MROW (NB*NA)      // 4096 anchor rows total
#define NQKV (3*DM)       // 2304
#define QBLK 32
#define ATTNB 1024        // attn compute blocks
#define PROLB 800         // prologue blocks

typedef __attribute__((ext_vector_type(4))) float f32x4;
typedef __attribute__((ext_vector_type(8))) short s16x8;

static __device__ __forceinline__ unsigned short f2bf(float x) {
  unsigned int u = __float_as_uint(x);
  u += 0x7fffu + ((u >> 16) & 1u);          // RNE
  return (unsigned short)(u >> 16);
}
static __device__ __forceinline__ float bf2f(unsigned short h) {
  return __uint_as_float(((unsigned int)h) << 16);
}

static __device__ __forceinline__ void gld_lds16(const void* g, void* l) {
  __builtin_amdgcn_global_load_lds(
      (const __attribute__((address_space(1))) unsigned int*)g,
      (__attribute__((address_space(3))) unsigned int*)l, 16, 0, 0);
}

// ---------------- prologue: gather+LN (wave/row) + weight convert + inline fill ----
__global__ __launch_bounds__(512) void prologue(
    const float* __restrict__ hs, const int* __restrict__ anc,
    const float* __restrict__ gam, const float* __restrict__ bet,
    const float* __restrict__ wq, const float* __restrict__ wk,
    const float* __restrict__ wv, const float* __restrict__ wo,
    unsigned short* __restrict__ xh,
    unsigned short* __restrict__ w1h, unsigned short* __restrict__ woh,
    f32x4* __restrict__ fillp, int fstart, int fend)
{
  const int bid = blockIdx.x;
  const int t = threadIdx.x;
  if (bid < 512) {
    const int w = t >> 6, lane = t & 63;
    const int r = bid * 8 + w;                 // anchor row 0..4095
    const int b = r >> 9, a = r & (NA - 1);
    const int idx = anc[b * NA + a];
    const float4* src4 = reinterpret_cast<const float4*>(hs + ((size_t)b * SEQ + idx) * DM);
    float4 e[3];
    float s = 0.f, ss = 0.f;
    #pragma unroll
    for (int p = 0; p < 3; ++p) {
      e[p] = src4[lane * 3 + p];
      s  += e[p].x + e[p].y + e[p].z + e[p].w;
      ss += e[p].x*e[p].x + e[p].y*e[p].y + e[p].z*e[p].z + e[p].w*e[p].w;
    }
    #pragma unroll
    for (int o = 1; o < 64; o <<= 1) { s += __shfl_xor(s, o); ss += __shfl_xor(ss, o); }
    const float mu = s * (1.f / DM);
    const float var = ss * (1.f / DM) - mu * mu;   // biased, matches jnp.var
    const float rstd = rsqrtf(var + 1e-5f);
    uint2* dst = reinterpret_cast<uint2*>(xh + (size_t)r * DM);
    const float4* g4 = reinterpret_cast<const float4*>(gam);
    const float4* b4 = reinterpret_cast<const float4*>(bet);
    #pragma unroll
    for (int p = 0; p < 3; ++p) {
      const float4 gv = g4[lane * 3 + p], bv = b4[lane * 3 + p];
      const float y0 = (e[p].x - mu) * rstd * gv.x + bv.x;
      const float y1 = (e[p].y - mu) * rstd * gv.y + bv.y;
      const float y2 = (e[p].z - mu) * rstd * gv.z + bv.z;
      const float y3 = (e[p].w - mu) * rstd * gv.w + bv.w;
      uint2 pk;
      pk.x = (unsigned)f2bf(y0) | ((unsigned)f2bf(y1) << 16);
      pk.y = (unsigned)f2bf(y2) | ((unsigned)f2bf(y3) << 16);
      dst[lane * 3 + p] = pk;
    }
  } else {
    const int base = (bid - 512) * 2048;       // float4 index base
    const int T1_4 = (NQKV * DM) / 4;          // 442368
    const int TW_4 = (DM * DM) / 4;            // 147456
    #pragma unroll
    for (int rep = 0; rep < 4; ++rep) {
      const int i = base + rep * 512 + t;
      float4 v; unsigned short* dh; int e4;
      if (i < T1_4) {
        v = (i < TW_4) ? reinterpret_cast<const float4*>(wq)[i]
          : (i < 2*TW_4) ? reinterpret_cast<const float4*>(wk)[i - TW_4]
                         : reinterpret_cast<const float4*>(wv)[i - 2*TW_4];
        dh = w1h; e4 = i;
      } else {
        const int j = i - T1_4;
        v = reinterpret_cast<const float4*>(wo)[j];
        dh = woh; e4 = j;
      }
      uint2 ph;
      ph.x = (unsigned)f2bf(v.x) | ((unsigned)f2bf(v.y) << 16);
      ph.y = (unsigned)f2bf(v.z) | ((unsigned)f2bf(v.w) << 16);
      reinterpret_cast<uint2*>(dh)[e4] = ph;
    }
  }
  // inline fill slice (runs in this block's completion stagger / latency shadow)
  {
    const f32x4 z = {0.f, 0.f, 0.f, 0.f};
    for (int i = fstart + bid * 512 + t; i < fend; i += PROLB * 512)
      __builtin_nontemporal_store(z, fillp + i);
  }
}

// ---------------- BMxBN single-bf16 NT GEMM template, BK=64 ----------------
// Each COMPUTE block writes a fill slice after its epilogue (drain-window overlap).
template<int EPI, int BM, int BN, int NCOMP, int GCOLS>
__global__ __launch_bounds__(256, 4) void gemm_t(
    const unsigned short* __restrict__ Ah,
    const unsigned short* __restrict__ Bh,
    const float* __restrict__ biasq, const float* __restrict__ biask, const float* __restrict__ biasv,
    unsigned short* __restrict__ qh,
    unsigned short* __restrict__ kh,
    unsigned short* __restrict__ vh,
    const float* __restrict__ biaso, const int* __restrict__ anc,
    float* __restrict__ outp,
    f32x4* __restrict__ fillp, int fstart, int fend)
{
  constexpr int MI = BM / 32, NJ = BN / 32;
  __shared__ unsigned short sA[BM * 64], sB[BN * 64];
  const int bidx = blockIdx.x;
  const int tid = threadIdx.x, lane = tid & 63, w = tid >> 6;
  const int wr = w >> 1, wc = w & 1;
  // bijective XCD swizzle (NCOMP % 8 == 0)
  const unsigned int wg = ((unsigned)bidx & 7) * (NCOMP >> 3) + ((unsigned)bidx >> 3);
  const int m0 = (int)(wg / GCOLS) * BM, n0 = (int)(wg % GCOLS) * BN;
  const int rsel = lane & 15, kg = lane >> 4;
  f32x4 acc[MI][NJ] = {};

  for (int k0 = 0; k0 < DM; k0 += 64) {
    __syncthreads();
    #pragma unroll
    for (int c = 0; c < (BM + BN) / 32; ++c) {
      const int gg = c * 256 + w * 64;           // wave-uniform granule base
      const int g = gg + lane;
      if (g < BM * 8) {
        const int row = g >> 3, slot = g & 7;
        const int kk = k0 + ((slot ^ (row & 7)) << 3);
        gld_lds16(Ah + (size_t)(m0 + row) * DM + kk, sA + gg * 8);
      } else {
        const int g2 = g - BM * 8;
        const int row = g2 >> 3, slot = g2 & 7;
        const int kk = k0 + ((slot ^ (row & 7)) << 3);
        gld_lds16(Bh + (size_t)(n0 + row) * DM + kk, sB + (gg - BM * 8) * 8);
      }
    }
    __syncthreads();
    #pragma unroll
    for (int s = 0; s < 2; ++s) {               // two K=32 sub-steps within BK=64
      s16x8 af[MI], bf[NJ];
      #pragma unroll
      for (int i = 0; i < MI; ++i) {
        const int row = wr * (MI * 16) + i * 16 + rsel;
        const int as = (((s << 2) | kg) ^ (row & 7));
        af[i] = *reinterpret_cast<const s16x8*>(sA + row * 64 + as * 8);
      }
      #pragma unroll
      for (int j = 0; j < NJ; ++j) {
        const int col = wc * (NJ * 16) + j * 16 + rsel;
        const int bs = (((s << 2) | kg) ^ (col & 7));
        bf[j] = *reinterpret_cast<const s16x8*>(sB + col * 64 + bs * 8);
      }
      #pragma unroll
      for (int i = 0; i < MI; ++i)
        #pragma unroll
        for (int j = 0; j < NJ; ++j)
          acc[i][j] = __builtin_amdgcn_mfma_f32_16x16x32_bf16(af[i], bf[j], acc[i][j], 0, 0, 0);
    }
  }

  #pragma unroll
  for (int i = 0; i < MI; ++i)
    #pragma unroll
    for (int j = 0; j < NJ; ++j)
      #pragma unroll
      for (int r = 0; r < 4; ++r) {
        const int row = m0 + wr * (MI * 16) + i * 16 + kg * 4 + r;  // C/D: row=(l>>4)*4+reg
        const int col = n0 + wc * (NJ * 16) + j * 16 + rsel;         //      col=l&15
        const float v = acc[i][j][r];
        const int b = row >> 9, a = row & (NA - 1);
        if (EPI == 1) {
          const int sec = (col >= 2 * DM) ? 2 : (col >= DM ? 1 : 0);
          const int f = col - sec * DM;
          const int hh = f / HDIM, d = f - hh * HDIM;
          const float* bp = (sec == 0) ? biasq : (sec == 1) ? biask : biasv;
          const float val = v + bp[f];
          const int bhh = b * NHEAD + hh;
          if (sec == 0) {
            const size_t o = ((size_t)bhh * NA + a) * HDIM + d; qh[o] = f2bf(val);
          } else if (sec == 1) {
            const size_t o = ((size_t)bhh * NA + a) * HDIM + d; kh[o] = f2bf(val);
          } else {
            const size_t o = ((size_t)bhh * HDIM + d) * NA + a; vh[o] = f2bf(val);  // V^T
          }
        } else {
          const int sidx = anc[b * NA + a];
          outp[((size_t)b * SEQ + sidx) * DM + col] = v + biaso[col];
        }
      }

  // inline fill slice (runs in this block's completion stagger)
  if (EPI == 1) {
    const f32x4 z = {0.f, 0.f, 0.f, 0.f};
    for (int i = fstart + bidx * 256 + tid; i < fend; i += NCOMP * 256)
      __builtin_nontemporal_store(z, fillp + i);
  }
}

// ---------------- fused attention: bf16 score/P buffer (32 KiB), inline fill ------
__global__ __launch_bounds__(512, 4) void attn_fused(
    const unsigned short* __restrict__ qh,
    const unsigned short* __restrict__ kh,
    const unsigned short* __restrict__ vh,
    unsigned short* __restrict__ oh,
    f32x4* __restrict__ fillp, int fstart, int fend)
{
  __shared__ unsigned short S[QBLK * 512];   // bf16 scores -> bf16 P. 32 KiB
  __shared__ float rsum_lds[QBLK];
  const int blk = blockIdx.x;
  const int xcd = blk & 7, slot = blk >> 3;
  const int qt = slot & 15, bh = (slot >> 4) * 8 + xcd;
  const int b = bh >> 3, h = bh & 7;
  const int tid = threadIdx.x, lane = tid & 63, w = tid >> 6;
  const int rt = w & 1, ctq = w >> 1;    // QK^T: rows rt*16.., ct in [ctq*8, ctq*8+8)
  const int rsel = lane & 15, kg = lane >> 4;
  const int q0 = qt * QBLK;

  // Q fragments for this wave's 16 rows (single bf16)
  s16x8 qf[3];
  {
    const size_t qrow = (size_t)bh * NA + q0 + rt * 16 + rsel;
    const unsigned short* qp = qh + qrow * HDIM + kg * 8;
    #pragma unroll
    for (int kc = 0; kc < 3; ++kc)
      qf[kc] = *reinterpret_cast<const s16x8*>(qp + kc * 32);
  }
  const float scale = 0.10206207261596575f;  // 1/sqrt(96)
  const unsigned short* kb_h = kh + (size_t)bh * NA * HDIM + (size_t)rsel * HDIM + kg * 8;

  #pragma unroll
  for (int ct2 = 0; ct2 < 8; ++ct2) {
    const int ct = ctq * 8 + ct2;
    f32x4 acc = {0.f, 0.f, 0.f, 0.f};
    const unsigned short* kp = kb_h + (size_t)(ct * 16) * HDIM;
    s16x8 kf0 = *reinterpret_cast<const s16x8*>(kp);
    s16x8 kf1 = *reinterpret_cast<const s16x8*>(kp + 32);
    s16x8 kf2 = *reinterpret_cast<const s16x8*>(kp + 64);
    acc = __builtin_amdgcn_mfma_f32_16x16x32_bf16(qf[0], kf0, acc, 0, 0, 0);
    acc = __builtin_amdgcn_mfma_f32_16x16x32_bf16(qf[1], kf1, acc, 0, 0, 0);
    acc = __builtin_amdgcn_mfma_f32_16x16x32_bf16(qf[2], kf2, acc, 0, 0, 0);
    #pragma unroll
    for (int r = 0; r < 4; ++r) {
      const int row = rt * 16 + kg * 4 + r;
      const int col = ct * 16 + rsel;
      S[row * 512 + (col ^ ((row & 7) << 3))] = f2bf(acc[r] * scale);
    }
  }
  __syncthreads();

  // softmax (no max-subtract): bf16 chunks, 16 lanes/row, 32 elems/lane.
  {
    const int row = w * 4 + (lane >> 4);
    const int sub = lane & 15;
    const int swz = (row & 7) << 3;
    unsigned short* rowp = &S[row * 512];
    float sum = 0.f;
    #pragma unroll
    for (int i = 0; i < 4; ++i) {
      const int c = sub * 8 + i * 128;
      s16x8* slotp = reinterpret_cast<s16x8*>(rowp + (c ^ swz));
      s16x8 u = *slotp;
      s16x8 pk;
      #pragma unroll
      for (int j = 0; j < 8; ++j) {
        float p = __expf(bf2f((unsigned short)u[j]));
        sum += p;
        pk[j] = (short)f2bf(p);
      }
      *slotp = pk;                            // in-place, same lane
    }
    sum += __shfl_xor(sum, 1);
    sum += __shfl_xor(sum, 2);
    sum += __shfl_xor(sum, 4);
    sum += __shfl_xor(sum, 8);
    if (sub == 0) rsum_lds[row] = 1.f / sum;
  }
  __syncthreads();

  // O = P V : 12 tasks (rt2 x nt) over 8 waves; P loaded directly as A-operand.
  const unsigned short* vb_h = vh + (size_t)bh * HDIM * NA + (size_t)rsel * NA + kg * 8;
  for (int task = w; task < 12; task += 8) {
    const int nt = task % 6, rt2 = task / 6;
    f32x4 acc = {0.f, 0.f, 0.f, 0.f};
    const int row = rt2 * 16 + rsel;
    const int swz = (row & 7) << 3;
    const unsigned short* rowp = &S[row * 512];
    const unsigned short* vp = vb_h + (size_t)(nt * 16) * NA;
    #pragma unroll
    for (int kc = 0; kc < 16; ++kc) {
      const int c = kc * 32 + kg * 8;
      s16x8 ph  = *reinterpret_cast<const s16x8*>(rowp + (c ^ swz));
      s16x8 vfh = *reinterpret_cast<const s16x8*>(vp + kc * 32);
      acc = __builtin_amdgcn_mfma_f32_16x16x32_bf16(ph, vfh, acc, 0, 0, 0);
    }
    #pragma unroll
    for (int r = 0; r < 4; ++r) {
      const float rinv = rsum_lds[rt2 * 16 + kg * 4 + r];
      const int rowg = b * NA + q0 + rt2 * 16 + kg * 4 + r;
      size_t o = (size_t)rowg * DM + h * HDIM + nt * 16 + rsel;
      oh[o] = f2bf(acc[r] * rinv);
    }
  }

  // inline fill slice (runs in this block's completion stagger)
  {
    const f32x4 z = {0.f, 0.f, 0.f, 0.f};
    for (int i = fstart + blk * 512 + tid; i < fend; i += ATTNB * 512)
      __builtin_nontemporal_store(z, fillp + i);
  }
}

extern "C" void kernel_launch(void* const* d_in, const int* in_sizes, int n_in,
                              void* d_out, int out_size, void* d_ws, size_t ws_size,
                              hipStream_t stream)
{
  const float* hs   = (const float*)d_in[0];
  const int*   anc  = (const int*)d_in[1];
  const float* ln_g = (const float*)d_in[2];
  const float* ln_b = (const float*)d_in[3];
  const float* wq = (const float*)d_in[4];
  const float* bq = (const float*)d_in[5];
  const float* wk = (const float*)d_in[6];
  const float* bk = (const float*)d_in[7];
  const float* wv = (const float*)d_in[8];
  const float* bv = (const float*)d_in[9];
  const float* wo = (const float*)d_in[10];
  const float* bo = (const float*)d_in[11];
  float* outp = (float*)d_out;

  char* ws = (char*)d_ws;
  size_t off = 0;
  auto take = [&](size_t bytes) { char* p = ws + off; off += (bytes + 255) & ~(size_t)255; return p; };
  unsigned short* xh  = (unsigned short*)take((size_t)MROW * DM * 2);
  unsigned short* w1h = (unsigned short*)take((size_t)NQKV * DM * 2);
  unsigned short* woh = (unsigned short*)take((size_t)DM * DM * 2);
  const size_t qkvsz = (size_t)NB * NHEAD * NA * HDIM * 2;
  unsigned short* qhb = (unsigned short*)take(qkvsz);
  unsigned short* khb = (unsigned short*)take(qkvsz);
  unsigned short* vhb = (unsigned short*)take(qkvsz);
  unsigned short* ohb = (unsigned short*)take((size_t)MROW * DM * 2);

  const int n4 = out_size / 4;
  const int f1 = n4 / 4;                          // prologue fills [0, 1/4)
  const int f2 = (int)(((long long)n4 * 5) / 8);  // gemm1 [1/4, 5/8), attn [5/8, 1)

  prologue<<<PROLB, 512, 0, stream>>>(
      hs, anc, ln_g, ln_b, wq, wk, wv, wo, xh, w1h, woh,
      (f32x4*)outp, 0, f1);
  // gemm1: 768 compute blocks (128x96, 3/CU balanced); inline fill slices
  gemm_t<1, 128, 96, 768, 24><<<768, 256, 0, stream>>>(
      xh, w1h, bq, bk, bv, qhb, khb, vhb,
      nullptr, nullptr, nullptr,
      (f32x4*)outp, f1, f2);
  attn_fused<<<ATTNB, 512, 0, stream>>>(
      qhb, khb, vhb, ohb, (f32x4*)outp, f2, n4);
  // gemm2: 64x96 tiles -> 512 compute blocks (2/CU balanced), no fill
  gemm_t<2, 64, 96, 512, 8><<<512, 256, 0, stream>>>(
      ohb, woh, nullptr, nullptr, nullptr,
      nullptr, nullptr, nullptr,
      bo, anc, outp,
      nullptr, 0, 0);
}

// Round 17
// 100.725 us; speedup vs baseline: 1.0029x; 1.0029x over previous
//
#include <hip/hip_runtime.h>

#define DM 768
#define NHEAD 8
#define HDIM 96
#define NB 8
#define SEQ 8192
#define NA 512
#define MROW (NB*NA)      // 4096 anchor rows total
#define NQKV (3*DM)       // 2304
#define QBLK 32
#define ATTNB 1024        // attn compute blocks
#define PROLB 800         // prologue blocks

typedef __attribute__((ext_vector_type(4))) float f32x4;
typedef __attribute__((ext_vector_type(8))) short s16x8;

static __device__ __forceinline__ unsigned short f2bf(float x) {
  unsigned int u = __float_as_uint(x);
  u += 0x7fffu + ((u >> 16) & 1u);          // RNE
  return (unsigned short)(u >> 16);
}
static __device__ __forceinline__ float bf2f(unsigned short h) {
  return __uint_as_float(((unsigned int)h) << 16);
}

static __device__ __forceinline__ void gld_lds16(const void* g, void* l) {
  __builtin_amdgcn_global_load_lds(
      (const __attribute__((address_space(1))) unsigned int*)g,
      (__attribute__((address_space(3))) unsigned int*)l, 16, 0, 0);
}

// ---------------- prologue: gather+LN (wave/row) + weight convert + inline fill ----
__global__ __launch_bounds__(512) void prologue(
    const float* __restrict__ hs, const int* __restrict__ anc,
    const float* __restrict__ gam, const float* __restrict__ bet,
    const float* __restrict__ wq, const float* __restrict__ wk,
    const float* __restrict__ wv, const float* __restrict__ wo,
    unsigned short* __restrict__ xh,
    unsigned short* __restrict__ w1h, unsigned short* __restrict__ woh,
    f32x4* __restrict__ fillp, int fstart, int fend)
{
  const int bid = blockIdx.x;
  const int t = threadIdx.x;
  if (bid < 512) {
    const int w = t >> 6, lane = t & 63;
    const int r = bid * 8 + w;                 // anchor row 0..4095
    const int b = r >> 9, a = r & (NA - 1);
    const int idx = anc[b * NA + a];
    const float4* src4 = reinterpret_cast<const float4*>(hs + ((size_t)b * SEQ + idx) * DM);
    float4 e[3];
    float s = 0.f, ss = 0.f;
    #pragma unroll
    for (int p = 0; p < 3; ++p) {
      e[p] = src4[lane * 3 + p];
      s  += e[p].x + e[p].y + e[p].z + e[p].w;
      ss += e[p].x*e[p].x + e[p].y*e[p].y + e[p].z*e[p].z + e[p].w*e[p].w;
    }
    #pragma unroll
    for (int o = 1; o < 64; o <<= 1) { s += __shfl_xor(s, o); ss += __shfl_xor(ss, o); }
    const float mu = s * (1.f / DM);
    const float var = ss * (1.f / DM) - mu * mu;   // biased, matches jnp.var
    const float rstd = rsqrtf(var + 1e-5f);
    uint2* dst = reinterpret_cast<uint2*>(xh + (size_t)r * DM);
    const float4* g4 = reinterpret_cast<const float4*>(gam);
    const float4* b4 = reinterpret_cast<const float4*>(bet);
    #pragma unroll
    for (int p = 0; p < 3; ++p) {
      const float4 gv = g4[lane * 3 + p], bv = b4[lane * 3 + p];
      const float y0 = (e[p].x - mu) * rstd * gv.x + bv.x;
      const float y1 = (e[p].y - mu) * rstd * gv.y + bv.y;
      const float y2 = (e[p].z - mu) * rstd * gv.z + bv.z;
      const float y3 = (e[p].w - mu) * rstd * gv.w + bv.w;
      uint2 pk;
      pk.x = (unsigned)f2bf(y0) | ((unsigned)f2bf(y1) << 16);
      pk.y = (unsigned)f2bf(y2) | ((unsigned)f2bf(y3) << 16);
      dst[lane * 3 + p] = pk;
    }
  } else {
    const int base = (bid - 512) * 2048;       // float4 index base
    const int T1_4 = (NQKV * DM) / 4;          // 442368
    const int TW_4 = (DM * DM) / 4;            // 147456
    #pragma unroll
    for (int rep = 0; rep < 4; ++rep) {
      const int i = base + rep * 512 + t;
      float4 v; unsigned short* dh; int e4;
      if (i < T1_4) {
        v = (i < TW_4) ? reinterpret_cast<const float4*>(wq)[i]
          : (i < 2*TW_4) ? reinterpret_cast<const float4*>(wk)[i - TW_4]
                         : reinterpret_cast<const float4*>(wv)[i - 2*TW_4];
        dh = w1h; e4 = i;
      } else {
        const int j = i - T1_4;
        v = reinterpret_cast<const float4*>(wo)[j];
        dh = woh; e4 = j;
      }
      uint2 ph;
      ph.x = (unsigned)f2bf(v.x) | ((unsigned)f2bf(v.y) << 16);
      ph.y = (unsigned)f2bf(v.z) | ((unsigned)f2bf(v.w) << 16);
      reinterpret_cast<uint2*>(dh)[e4] = ph;
    }
  }
  // inline fill slice (runs in this block's completion stagger / latency shadow)
  {
    const f32x4 z = {0.f, 0.f, 0.f, 0.f};
    for (int i = fstart + bid * 512 + t; i < fend; i += PROLB * 512)
      __builtin_nontemporal_store(z, fillp + i);
  }
}

// ---------------- BMxBN single-bf16 NT GEMM template, BK=64 ----------------
// Each COMPUTE block writes a fill slice after its epilogue (drain-window overlap).
template<int EPI, int BM, int BN, int NCOMP, int GCOLS>
__global__ __launch_bounds__(256, 4) void gemm_t(
    const unsigned short* __restrict__ Ah,
    const unsigned short* __restrict__ Bh,
    const float* __restrict__ biasq, const float* __restrict__ biask, const float* __restrict__ biasv,
    unsigned short* __restrict__ qh,
    unsigned short* __restrict__ kh,
    unsigned short* __restrict__ vh,
    const float* __restrict__ biaso, const int* __restrict__ anc,
    float* __restrict__ outp,
    f32x4* __restrict__ fillp, int fstart, int fend)
{
  constexpr int MI = BM / 32, NJ = BN / 32;
  __shared__ unsigned short sA[BM * 64], sB[BN * 64];
  const int bidx = blockIdx.x;
  const int tid = threadIdx.x, lane = tid & 63, w = tid >> 6;
  const int wr = w >> 1, wc = w & 1;
  // bijective XCD swizzle (NCOMP % 8 == 0)
  const unsigned int wg = ((unsigned)bidx & 7) * (NCOMP >> 3) + ((unsigned)bidx >> 3);
  const int m0 = (int)(wg / GCOLS) * BM, n0 = (int)(wg % GCOLS) * BN;
  const int rsel = lane & 15, kg = lane >> 4;
  f32x4 acc[MI][NJ] = {};

  for (int k0 = 0; k0 < DM; k0 += 64) {
    __syncthreads();
    #pragma unroll
    for (int c = 0; c < (BM + BN) / 32; ++c) {
      const int gg = c * 256 + w * 64;           // wave-uniform granule base
      const int g = gg + lane;
      if (g < BM * 8) {
        const int row = g >> 3, slot = g & 7;
        const int kk = k0 + ((slot ^ (row & 7)) << 3);
        gld_lds16(Ah + (size_t)(m0 + row) * DM + kk, sA + gg * 8);
      } else {
        const int g2 = g - BM * 8;
        const int row = g2 >> 3, slot = g2 & 7;
        const int kk = k0 + ((slot ^ (row & 7)) << 3);
        gld_lds16(Bh + (size_t)(n0 + row) * DM + kk, sB + (gg - BM * 8) * 8);
      }
    }
    __syncthreads();
    #pragma unroll
    for (int s = 0; s < 2; ++s) {               // two K=32 sub-steps within BK=64
      s16x8 af[MI], bf[NJ];
      #pragma unroll
      for (int i = 0; i < MI; ++i) {
        const int row = wr * (MI * 16) + i * 16 + rsel;
        const int as = (((s << 2) | kg) ^ (row & 7));
        af[i] = *reinterpret_cast<const s16x8*>(sA + row * 64 + as * 8);
      }
      #pragma unroll
      for (int j = 0; j < NJ; ++j) {
        const int col = wc * (NJ * 16) + j * 16 + rsel;
        const int bs = (((s << 2) | kg) ^ (col & 7));
        bf[j] = *reinterpret_cast<const s16x8*>(sB + col * 64 + bs * 8);
      }
      #pragma unroll
      for (int i = 0; i < MI; ++i)
        #pragma unroll
        for (int j = 0; j < NJ; ++j)
          acc[i][j] = __builtin_amdgcn_mfma_f32_16x16x32_bf16(af[i], bf[j], acc[i][j], 0, 0, 0);
    }
  }

  #pragma unroll
  for (int i = 0; i < MI; ++i)
    #pragma unroll
    for (int j = 0; j < NJ; ++j)
      #pragma unroll
      for (int r = 0; r < 4; ++r) {
        const int row = m0 + wr * (MI * 16) + i * 16 + kg * 4 + r;  // C/D: row=(l>>4)*4+reg
        const int col = n0 + wc * (NJ * 16) + j * 16 + rsel;         //      col=l&15
        const float v = acc[i][j][r];
        const int b = row >> 9, a = row & (NA - 1);
        if (EPI == 1) {
          const int sec = (col >= 2 * DM) ? 2 : (col >= DM ? 1 : 0);
          const int f = col - sec * DM;
          const int hh = f / HDIM, d = f - hh * HDIM;
          const float* bp = (sec == 0) ? biasq : (sec == 1) ? biask : biasv;
          const float val = v + bp[f];
          const int bhh = b * NHEAD + hh;
          if (sec == 0) {
            const size_t o = ((size_t)bhh * NA + a) * HDIM + d; qh[o] = f2bf(val);
          } else if (sec == 1) {
            const size_t o = ((size_t)bhh * NA + a) * HDIM + d; kh[o] = f2bf(val);
          } else {
            const size_t o = ((size_t)bhh * HDIM + d) * NA + a; vh[o] = f2bf(val);  // V^T
          }
        } else {
          const int sidx = anc[b * NA + a];
          outp[((size_t)b * SEQ + sidx) * DM + col] = v + biaso[col];
        }
      }

  // inline fill slice (runs in this block's completion stagger)
  if (EPI == 1) {
    const f32x4 z = {0.f, 0.f, 0.f, 0.f};
    for (int i = fstart + bidx * 256 + tid; i < fend; i += NCOMP * 256)
      __builtin_nontemporal_store(z, fillp + i);
  }
}

// ---------------- fused attention: bf16 score/P buffer (32 KiB), inline fill ------
__global__ __launch_bounds__(512, 4) void attn_fused(
    const unsigned short* __restrict__ qh,
    const unsigned short* __restrict__ kh,
    const unsigned short* __restrict__ vh,
    unsigned short* __restrict__ oh,
    f32x4* __restrict__ fillp, int fstart, int fend)
{
  __shared__ unsigned short S[QBLK * 512];   // bf16 scores -> bf16 P. 32 KiB
  __shared__ float rsum_lds[QBLK];
  const int blk = blockIdx.x;
  const int xcd = blk & 7, slot = blk >> 3;
  const int qt = slot & 15, bh = (slot >> 4) * 8 + xcd;
  const int b = bh >> 3, h = bh & 7;
  const int tid = threadIdx.x, lane = tid & 63, w = tid >> 6;
  const int rt = w & 1, ctq = w >> 1;    // QK^T: rows rt*16.., ct in [ctq*8, ctq*8+8)
  const int rsel = lane & 15, kg = lane >> 4;
  const int q0 = qt * QBLK;

  // Q fragments for this wave's 16 rows (single bf16)
  s16x8 qf[3];
  {
    const size_t qrow = (size_t)bh * NA + q0 + rt * 16 + rsel;
    const unsigned short* qp = qh + qrow * HDIM + kg * 8;
    #pragma unroll
    for (int kc = 0; kc < 3; ++kc)
      qf[kc] = *reinterpret_cast<const s16x8*>(qp + kc * 32);
  }
  const float scale = 0.10206207261596575f;  // 1/sqrt(96)
  const unsigned short* kb_h = kh + (size_t)bh * NA * HDIM + (size_t)rsel * HDIM + kg * 8;

  #pragma unroll
  for (int ct2 = 0; ct2 < 8; ++ct2) {
    const int ct = ctq * 8 + ct2;
    f32x4 acc = {0.f, 0.f, 0.f, 0.f};
    const unsigned short* kp = kb_h + (size_t)(ct * 16) * HDIM;
    s16x8 kf0 = *reinterpret_cast<const s16x8*>(kp);
    s16x8 kf1 = *reinterpret_cast<const s16x8*>(kp + 32);
    s16x8 kf2 = *reinterpret_cast<const s16x8*>(kp + 64);
    acc = __builtin_amdgcn_mfma_f32_16x16x32_bf16(qf[0], kf0, acc, 0, 0, 0);
    acc = __builtin_amdgcn_mfma_f32_16x16x32_bf16(qf[1], kf1, acc, 0, 0, 0);
    acc = __builtin_amdgcn_mfma_f32_16x16x32_bf16(qf[2], kf2, acc, 0, 0, 0);
    #pragma unroll
    for (int r = 0; r < 4; ++r) {
      const int row = rt * 16 + kg * 4 + r;
      const int col = ct * 16 + rsel;
      S[row * 512 + (col ^ ((row & 7) << 3))] = f2bf(acc[r] * scale);
    }
  }
  __syncthreads();

  // softmax (no max-subtract): bf16 chunks, 16 lanes/row, 32 elems/lane.
  {
    const int row = w * 4 + (lane >> 4);
    const int sub = lane & 15;
    const int swz = (row & 7) << 3;
    unsigned short* rowp = &S[row * 512];
    float sum = 0.f;
    #pragma unroll
    for (int i = 0; i < 4; ++i) {
      const int c = sub * 8 + i * 128;
      s16x8* slotp = reinterpret_cast<s16x8*>(rowp + (c ^ swz));
      s16x8 u = *slotp;
      s16x8 pk;
      #pragma unroll
      for (int j = 0; j < 8; ++j) {
        float p = __expf(bf2f((unsigned short)u[j]));
        sum += p;
        pk[j] = (short)f2bf(p);
      }
      *slotp = pk;                            // in-place, same lane
    }
    sum += __shfl_xor(sum, 1);
    sum += __shfl_xor(sum, 2);
    sum += __shfl_xor(sum, 4);
    sum += __shfl_xor(sum, 8);
    if (sub == 0) rsum_lds[row] = 1.f / sum;
  }
  __syncthreads();

  // O = P V : 12 tasks (rt2 x nt) over 8 waves; P loaded directly as A-operand.
  const unsigned short* vb_h = vh + (size_t)bh * HDIM * NA + (size_t)rsel * NA + kg * 8;
  for (int task = w; task < 12; task += 8) {
    const int nt = task % 6, rt2 = task / 6;
    f32x4 acc = {0.f, 0.f, 0.f, 0.f};
    const int row = rt2 * 16 + rsel;
    const int swz = (row & 7) << 3;
    const unsigned short* rowp = &S[row * 512];
    const unsigned short* vp = vb_h + (size_t)(nt * 16) * NA;
    #pragma unroll
    for (int kc = 0; kc < 16; ++kc) {
      const int c = kc * 32 + kg * 8;
      s16x8 ph  = *reinterpret_cast<const s16x8*>(rowp + (c ^ swz));
      s16x8 vfh = *reinterpret_cast<const s16x8*>(vp + kc * 32);
      acc = __builtin_amdgcn_mfma_f32_16x16x32_bf16(ph, vfh, acc, 0, 0, 0);
    }
    #pragma unroll
    for (int r = 0; r < 4; ++r) {
      const float rinv = rsum_lds[rt2 * 16 + kg * 4 + r];
      const int rowg = b * NA + q0 + rt2 * 16 + kg * 4 + r;
      size_t o = (size_t)rowg * DM + h * HDIM + nt * 16 + rsel;
      oh[o] = f2bf(acc[r] * rinv);
    }
  }

  // inline fill slice (runs in this block's completion stagger)
  {
    const f32x4 z = {0.f, 0.f, 0.f, 0.f};
    for (int i = fstart + blk * 512 + tid; i < fend; i += ATTNB * 512)
      __builtin_nontemporal_store(z, fillp + i);
  }
}

extern "C" void kernel_launch(void* const* d_in, const int* in_sizes, int n_in,
                              void* d_out, int out_size, void* d_ws, size_t ws_size,
                              hipStream_t stream)
{
  const float* hs   = (const float*)d_in[0];
  const int*   anc  = (const int*)d_in[1];
  const float* ln_g = (const float*)d_in[2];
  const float* ln_b = (const float*)d_in[3];
  const float* wq = (const float*)d_in[4];
  const float* bq = (const float*)d_in[5];
  const float* wk = (const float*)d_in[6];
  const float* bk = (const float*)d_in[7];
  const float* wv = (const float*)d_in[8];
  const float* bv = (const float*)d_in[9];
  const float* wo = (const float*)d_in[10];
  const float* bo = (const float*)d_in[11];
  float* outp = (float*)d_out;

  char* ws = (char*)d_ws;
  size_t off = 0;
  auto take = [&](size_t bytes) { char* p = ws + off; off += (bytes + 255) & ~(size_t)255; return p; };
  unsigned short* xh  = (unsigned short*)take((size_t)MROW * DM * 2);
  unsigned short* w1h = (unsigned short*)take((size_t)NQKV * DM * 2);
  unsigned short* woh = (unsigned short*)take((size_t)DM * DM * 2);
  const size_t qkvsz = (size_t)NB * NHEAD * NA * HDIM * 2;
  unsigned short* qhb = (unsigned short*)take(qkvsz);
  unsigned short* khb = (unsigned short*)take(qkvsz);
  unsigned short* vhb = (unsigned short*)take(qkvsz);
  unsigned short* ohb = (unsigned short*)take((size_t)MROW * DM * 2);

  const int n4 = out_size / 4;
  const int f1 = n4 / 4;                          // prologue fills [0, 1/4)
  const int f2 = (int)(((long long)n4 * 5) / 8);  // gemm1 [1/4, 5/8), attn [5/8, 1)

  prologue<<<PROLB, 512, 0, stream>>>(
      hs, anc, ln_g, ln_b, wq, wk, wv, wo, xh, w1h, woh,
      (f32x4*)outp, 0, f1);
  // gemm1: 64x96 tiles -> 64*24 = 1536 blocks (4/CU co-res + 2 backfill waves)
  gemm_t<1, 64, 96, 1536, 24><<<1536, 256, 0, stream>>>(
      xh, w1h, bq, bk, bv, qhb, khb, vhb,
      nullptr, nullptr, nullptr,
      (f32x4*)outp, f1, f2);
  attn_fused<<<ATTNB, 512, 0, stream>>>(
      qhb, khb, vhb, ohb, (f32x4*)outp, f2, n4);
  // gemm2: 32x96 tiles -> 128*8 = 1024 blocks (4/CU co-resident)
  gemm_t<2, 32, 96, 1024, 8><<<1024, 256, 0, stream>>>(
      ohb, woh, nullptr, nullptr, nullptr,
      nullptr, nullptr, nullptr,
      bo, anc, outp,
      nullptr, 0, 0);
}